// Round 1
// baseline (1342.101 us; speedup 1.0000x reference)
//
#include <hip/hip_runtime.h>
#include <math.h>

typedef __attribute__((ext_vector_type(8))) short short8;
typedef __attribute__((ext_vector_type(4))) float f32x4;
typedef __attribute__((ext_vector_type(4))) float f4;
typedef __attribute__((ext_vector_type(4))) unsigned short us4;
typedef unsigned short u16;

#define Bn 32
#define Ln 128
#define Dn 512
#define LATn 256
#define Vn 50257
#define VPAD 50304
#define DFn 2048
#define Hn 8
#define HDn 64

__device__ __forceinline__ u16 f2bf(float f) {
  union { float f; unsigned u; } v; v.f = f;
  unsigned r = 0x7FFFu + ((v.u >> 16) & 1u);
  return (u16)((v.u + r) >> 16);
}

// ---------------- f32 -> bf16 conversion (weights), with zero-padded tail ----
__global__ void k_cvt_bf16(const f4* __restrict__ in, us4* __restrict__ out,
                           int n4, int n4pad) {
  int i = blockIdx.x * blockDim.x + threadIdx.x;
  int stride = gridDim.x * blockDim.x;
  for (; i < n4pad; i += stride) {
    us4 o;
    if (i < n4) {
      f4 v = in[i];
      o[0] = f2bf(v[0]); o[1] = f2bf(v[1]); o[2] = f2bf(v[2]); o[3] = f2bf(v[3]);
    } else {
      o[0] = 0; o[1] = 0; o[2] = 0; o[3] = 0;
    }
    out[i] = o;
  }
}

// ---------------- latent_proj: mem = LN(GELU(z @ lp_w.T + lp_b)) -------------
__global__ __launch_bounds__(256)
void k_latent_mem(const float* __restrict__ z, const float* __restrict__ lp_w,
                  const float* __restrict__ lp_b, const float* __restrict__ g,
                  const float* __restrict__ be, float* __restrict__ mem) {
  __shared__ float zs[LATn];
  __shared__ float red[16];
  int b = blockIdx.x, t = threadIdx.x;
  zs[t] = z[b * LATn + t];
  __syncthreads();
  float h[2];
  #pragma unroll
  for (int j = 0; j < 2; j++) {
    int oj = t + j * 256;
    const float* w = lp_w + (size_t)oj * LATn;
    float s0 = 0, s1 = 0, s2 = 0, s3 = 0;
    for (int k = 0; k < LATn; k += 4) {
      s0 += zs[k] * w[k]; s1 += zs[k+1] * w[k+1];
      s2 += zs[k+2] * w[k+2]; s3 += zs[k+3] * w[k+3];
    }
    float x = s0 + s1 + s2 + s3 + lp_b[oj];
    h[j] = 0.5f * x * (1.0f + erff(x * 0.70710678118654752f));
  }
  float sum = h[0] + h[1], sq = h[0]*h[0] + h[1]*h[1];
  for (int off = 32; off; off >>= 1) {
    sum += __shfl_down(sum, off, 64);
    sq  += __shfl_down(sq,  off, 64);
  }
  int lane = t & 63, wid = t >> 6;
  if (!lane) { red[wid] = sum; red[8 + wid] = sq; }
  __syncthreads();
  float ts = red[0] + red[1] + red[2] + red[3];
  float tq = red[8] + red[9] + red[10] + red[11];
  float mu = ts * (1.0f / Dn);
  float var = tq * (1.0f / Dn) - mu * mu;
  float rstd = rsqrtf(fmaxf(var, 0.0f) + 1e-5f);
  #pragma unroll
  for (int j = 0; j < 2; j++) {
    int oj = t + j * 256;
    mem[b * Dn + oj] = (h[j] - mu) * rstd * g[oj] + be[oj];
  }
}

// ------------- cross-attention precompute (Lk=1 => softmax==1 => o = v) -----
// ca_add[i][b][:] = (mem[b] @ Wv_i.T + bv_i) @ Wo_i.T + bo_i
__global__ __launch_bounds__(256)
void k_ca(const float* __restrict__ mem, const float* __restrict__ ca_qkv_w,
          const float* __restrict__ ca_qkv_b, const float* __restrict__ ca_out_w,
          const float* __restrict__ ca_out_b, float* __restrict__ ca_add) {
  int blk = blockIdx.x;
  int i = blk >> 5, b = blk & 31, t = threadIdx.x;
  __shared__ float ms[Dn];
  __shared__ float vs[Dn];
  ms[t] = mem[b * Dn + t];
  ms[t + 256] = mem[b * Dn + t + 256];
  __syncthreads();
  const float* wv = ca_qkv_w + ((size_t)i * 1536 + 1024) * Dn;
  const float* bv = ca_qkv_b + i * 1536 + 1024;
  for (int j = t; j < Dn; j += 256) {
    const float* w = wv + (size_t)j * Dn;
    float s0 = 0, s1 = 0, s2 = 0, s3 = 0;
    for (int k = 0; k < Dn; k += 4) {
      s0 += ms[k]*w[k]; s1 += ms[k+1]*w[k+1]; s2 += ms[k+2]*w[k+2]; s3 += ms[k+3]*w[k+3];
    }
    vs[j] = s0 + s1 + s2 + s3 + bv[j];
  }
  __syncthreads();
  const float* wo = ca_out_w + (size_t)i * Dn * Dn;
  const float* bo = ca_out_b + i * Dn;
  for (int j = t; j < Dn; j += 256) {
    const float* w = wo + (size_t)j * Dn;
    float s0 = 0, s1 = 0, s2 = 0, s3 = 0;
    for (int k = 0; k < Dn; k += 4) {
      s0 += vs[k]*w[k]; s1 += vs[k+1]*w[k+1]; s2 += vs[k+2]*w[k+2]; s3 += vs[k+3]*w[k+3];
    }
    ca_add[((size_t)i * Bn + b) * Dn + j] = s0 + s1 + s2 + s3 + bo[j];
  }
}

// ---------------- embedding: X = tok_emb[ids] + pos_emb ---------------------
__global__ __launch_bounds__(128)
void k_embed(const int* __restrict__ ids, const float* __restrict__ tok,
             const float* __restrict__ pos, float* __restrict__ X,
             u16* __restrict__ Xb) {
  int r = blockIdx.x;
  int l = r & (Ln - 1);
  int id = ids[r];
  int c = threadIdx.x * 4;
  f4 te = *(const f4*)&tok[(size_t)id * Dn + c];
  f4 pe = *(const f4*)&pos[(size_t)l * Dn + c];
  f4 v = te + pe;
  *(f4*)&X[(size_t)r * Dn + c] = v;
  us4 o = { f2bf(v[0]), f2bf(v[1]), f2bf(v[2]), f2bf(v[3]) };
  *(us4*)&Xb[(size_t)r * Dn + c] = o;
}

// ---------------- fused residual add + LayerNorm -----------------------------
// CA=0: Y is per-row (M x 512).  CA=1: Y is per-batch broadcast (B x 512).
template <int CA>
__global__ __launch_bounds__(128)
void k_add_ln(float* __restrict__ X, u16* __restrict__ Xb,
              const float* __restrict__ Y, const float* __restrict__ g,
              const float* __restrict__ be) {
  int r = blockIdx.x, t = threadIdx.x;
  int c = t * 4;
  const float* yrow = CA ? (Y + (size_t)(r >> 7) * Dn) : (Y + (size_t)r * Dn);
  f4 x = *(const f4*)&X[(size_t)r * Dn + c];
  f4 y = *(const f4*)&yrow[c];
  f4 v = x + y;
  float sum = v[0] + v[1] + v[2] + v[3];
  float sq = v[0]*v[0] + v[1]*v[1] + v[2]*v[2] + v[3]*v[3];
  for (int off = 32; off; off >>= 1) {
    sum += __shfl_down(sum, off, 64);
    sq  += __shfl_down(sq,  off, 64);
  }
  __shared__ float red[4];
  int lane = t & 63, w = t >> 6;
  if (!lane) { red[w] = sum; red[2 + w] = sq; }
  __syncthreads();
  sum = red[0] + red[1]; sq = red[2] + red[3];
  float mu = sum * (1.0f / Dn);
  float var = sq * (1.0f / Dn) - mu * mu;
  float rstd = rsqrtf(fmaxf(var, 0.0f) + 1e-5f);
  f4 gg = *(const f4*)&g[c];
  f4 bb = *(const f4*)&be[c];
  f4 o = (v - mu) * rstd * gg + bb;
  *(f4*)&X[(size_t)r * Dn + c] = o;
  us4 ob = { f2bf(o[0]), f2bf(o[1]), f2bf(o[2]), f2bf(o[3]) };
  *(us4*)&Xb[(size_t)r * Dn + c] = ob;
}

// ---------------- causal self-attention, one (b,h) per block -----------------
__global__ __launch_bounds__(128)
void k_attn(const float* __restrict__ QKV, u16* __restrict__ Ob) {
  int bh = blockIdx.x;
  int b = bh >> 3, h = bh & 7;
  int t = threadIdx.x;  // q row
  __shared__ float Ks[Ln][HDn];
  __shared__ float Vs[Ln][HDn];
  __shared__ float Ss[Ln][Ln + 1];
  const float* base = QKV + (size_t)(b * Ln + t) * 1536;
  const float* krow = base + 512 + h * HDn;
  const float* vrow = base + 1024 + h * HDn;
  #pragma unroll
  for (int i = 0; i < HDn; i += 4) {
    *(f4*)&Ks[t][i] = *(const f4*)&krow[i];
    *(f4*)&Vs[t][i] = *(const f4*)&vrow[i];
  }
  float q[HDn];
  const float* qrow = base + h * HDn;
  #pragma unroll
  for (int i = 0; i < HDn; i += 4) {
    f4 v = *(const f4*)&qrow[i];
    q[i] = v[0]; q[i+1] = v[1]; q[i+2] = v[2]; q[i+3] = v[3];
  }
  __syncthreads();
  float m = -1e30f;
  for (int k = 0; k <= t; k++) {
    float s0 = 0, s1 = 0, s2 = 0, s3 = 0;
    #pragma unroll
    for (int i = 0; i < HDn; i += 4) {
      s0 += q[i] * Ks[k][i];   s1 += q[i+1] * Ks[k][i+1];
      s2 += q[i+2] * Ks[k][i+2]; s3 += q[i+3] * Ks[k][i+3];
    }
    float s = (s0 + s1 + s2 + s3) * 0.125f;
    Ss[t][k] = s;
    m = fmaxf(m, s);
  }
  float l = 0.0f;
  for (int k = 0; k <= t; k++) {
    float p = __expf(Ss[t][k] - m);
    Ss[t][k] = p;
    l += p;
  }
  float inv = 1.0f / l;
  float o[HDn] = {0};
  for (int k = 0; k <= t; k++) {
    float p = Ss[t][k];
    #pragma unroll
    for (int i = 0; i < HDn; i += 4) {
      o[i]   += p * Vs[k][i];   o[i+1] += p * Vs[k][i+1];
      o[i+2] += p * Vs[k][i+2]; o[i+3] += p * Vs[k][i+3];
    }
  }
  u16* orow = Ob + (size_t)(b * Ln + t) * Dn + h * HDn;
  #pragma unroll
  for (int i = 0; i < HDn; i += 4) {
    us4 v = { f2bf(o[i] * inv), f2bf(o[i+1] * inv),
              f2bf(o[i+2] * inv), f2bf(o[i+3] * inv) };
    *(us4*)&orow[i] = v;
  }
}

// ---------------- bf16 MFMA GEMM: C = A(MxK) * W(NxK)^T + bias ---------------
// m97 structure: 128x128 tile, BK=32, 4 waves (2x2), global_load_lds width 16.
// EPI 0: f32 store (+bias).  EPI 1: relu(+bias) -> bf16 store.
template <int EPI>
__global__ __launch_bounds__(256, 2)
void k_gemm_bt(const u16* __restrict__ A, const u16* __restrict__ Bw,
               const float* __restrict__ bias, void* __restrict__ Cout,
               int M, int N, int K, int ldc) {
  __shared__ u16 As[128 * 32];
  __shared__ u16 Bs[128 * 32];
  int bm = blockIdx.x, bn = blockIdx.y;
  int tid = threadIdx.x;
  int lane = tid & 63;
  int wid = tid >> 6;
  int wr = wid >> 1, wc = wid & 1;
  f32x4 acc[4][4] = {};

  int c0 = tid, c1 = tid + 256;
  const u16* a0 = A + (size_t)(bm * 128 + (c0 >> 2)) * K + (c0 & 3) * 8;
  const u16* a1 = A + (size_t)(bm * 128 + (c1 >> 2)) * K + (c1 & 3) * 8;
  const u16* b0 = Bw + (size_t)(bn * 128 + (c0 >> 2)) * K + (c0 & 3) * 8;
  const u16* b1 = Bw + (size_t)(bn * 128 + (c1 >> 2)) * K + (c1 & 3) * 8;
  char* lA0 = (char*)As + c0 * 16;
  char* lA1 = (char*)As + c1 * 16;
  char* lB0 = (char*)Bs + c0 * 16;
  char* lB1 = (char*)Bs + c1 * 16;
  int fr = lane & 15, kq = (lane >> 4) * 8;

  for (int k0 = 0; k0 < K; k0 += 32) {
    __syncthreads();
    __builtin_amdgcn_global_load_lds(
        (const __attribute__((address_space(1))) unsigned int*)(a0 + k0),
        (__attribute__((address_space(3))) unsigned int*)lA0, 16, 0, 0);
    __builtin_amdgcn_global_load_lds(
        (const __attribute__((address_space(1))) unsigned int*)(a1 + k0),
        (__attribute__((address_space(3))) unsigned int*)lA1, 16, 0, 0);
    __builtin_amdgcn_global_load_lds(
        (const __attribute__((address_space(1))) unsigned int*)(b0 + k0),
        (__attribute__((address_space(3))) unsigned int*)lB0, 16, 0, 0);
    __builtin_amdgcn_global_load_lds(
        (const __attribute__((address_space(1))) unsigned int*)(b1 + k0),
        (__attribute__((address_space(3))) unsigned int*)lB1, 16, 0, 0);
    __syncthreads();
    short8 av[4], bv[4];
    #pragma unroll
    for (int mi = 0; mi < 4; mi++)
      av[mi] = *(const short8*)&As[(wr * 64 + mi * 16 + fr) * 32 + kq];
    #pragma unroll
    for (int nj = 0; nj < 4; nj++)
      bv[nj] = *(const short8*)&Bs[(wc * 64 + nj * 16 + fr) * 32 + kq];
    #pragma unroll
    for (int mi = 0; mi < 4; mi++)
      #pragma unroll
      for (int nj = 0; nj < 4; nj++)
        acc[mi][nj] = __builtin_amdgcn_mfma_f32_16x16x32_bf16(
            av[mi], bv[nj], acc[mi][nj], 0, 0, 0);
  }

  int rbase = bm * 128 + wr * 64 + (lane >> 4) * 4;
  int cbase = bn * 128 + wc * 64 + fr;
  #pragma unroll
  for (int nj = 0; nj < 4; nj++) {
    int col = cbase + nj * 16;
    if (col >= N) continue;
    float bb = bias[col];
    #pragma unroll
    for (int mi = 0; mi < 4; mi++) {
      int row = rbase + mi * 16;
      #pragma unroll
      for (int r = 0; r < 4; r++) {
        float v = acc[mi][nj][r] + bb;
        if (EPI == 1) {
          v = fmaxf(v, 0.0f);
          ((u16*)Cout)[(size_t)(row + r) * ldc + col] = f2bf(v);
        } else {
          ((float*)Cout)[(size_t)(row + r) * ldc + col] = v;
        }
      }
    }
  }
}

// =============================================================================
extern "C" void kernel_launch(void* const* d_in, const int* in_sizes, int n_in,
                              void* d_out, int out_size, void* d_ws, size_t ws_size,
                              hipStream_t stream) {
  const float* z        = (const float*)d_in[0];
  const int*   ids      = (const int*)d_in[1];
  const float* tok      = (const float*)d_in[2];
  const float* pos      = (const float*)d_in[3];
  const float* lp_w     = (const float*)d_in[4];
  const float* lp_b     = (const float*)d_in[5];
  const float* lp_g     = (const float*)d_in[6];
  const float* lp_be    = (const float*)d_in[7];
  const float* sa_qkv_w = (const float*)d_in[8];
  const float* sa_qkv_b = (const float*)d_in[9];
  const float* sa_out_w = (const float*)d_in[10];
  const float* sa_out_b = (const float*)d_in[11];
  const float* ca_qkv_w = (const float*)d_in[12];
  const float* ca_qkv_b = (const float*)d_in[13];
  const float* ca_out_w = (const float*)d_in[14];
  const float* ca_out_b = (const float*)d_in[15];
  const float* ln1_g    = (const float*)d_in[16];
  const float* ln1_b    = (const float*)d_in[17];
  const float* ln2_g    = (const float*)d_in[18];
  const float* ln2_b    = (const float*)d_in[19];
  const float* ln3_g    = (const float*)d_in[20];
  const float* ln3_b    = (const float*)d_in[21];
  const float* ff1_w    = (const float*)d_in[22];
  const float* ff1_b    = (const float*)d_in[23];
  const float* ff2_w    = (const float*)d_in[24];
  const float* ff2_b    = (const float*)d_in[25];
  const float* op_w     = (const float*)d_in[26];
  const float* op_b     = (const float*)d_in[27];

  char* ws = (char*)d_ws;
  float* X      = (float*)(ws + 0);          //  4096x512 f32
  float* Y      = (float*)(ws + 8388608);    //  4096x512 f32
  float* QKV    = (float*)(ws + 16777216);   //  4096x1536 f32
  u16*   Xb     = (u16*)(ws + 41943040);     //  4096x512 bf16
  u16*   Ob     = (u16*)(ws + 46137344);     //  4096x512 bf16
  u16*   H1b    = (u16*)(ws + 50331648);     //  4096x2048 bf16
  u16*   Wb     = (u16*)(ws + 67108864);     //  50304x512 bf16 (weight arena)
  float* mem    = (float*)(ws + 118620160);  //  32x512 f32
  float* ca_add = (float*)(ws + 118685696);  //  4x32x512 f32

  k_latent_mem<<<Bn, 256, 0, stream>>>(z, lp_w, lp_b, lp_g, lp_be, mem);
  k_ca<<<4 * Bn, 256, 0, stream>>>(mem, ca_qkv_w, ca_qkv_b, ca_out_w, ca_out_b, ca_add);
  k_embed<<<Bn * Ln, 128, 0, stream>>>(ids, tok, pos, X, Xb);

  auto cvt = [&](const float* src, int n, int npad) {
    int n4 = n / 4, n4p = npad / 4;
    int blocks = (n4p + 255) / 256;
    if (blocks > 2048) blocks = 2048;
    k_cvt_bf16<<<blocks, 256, 0, stream>>>((const f4*)src, (us4*)Wb, n4, n4p);
  };

  const int M = Bn * Ln;  // 4096
  for (int i = 0; i < 4; i++) {
    // self-attention QKV projection
    cvt(sa_qkv_w + (size_t)i * 1536 * Dn, 1536 * Dn, 1536 * Dn);
    k_gemm_bt<0><<<dim3(M / 128, 1536 / 128), 256, 0, stream>>>(
        Xb, Wb, sa_qkv_b + i * 1536, QKV, M, 1536, Dn, 1536);
    // causal attention
    k_attn<<<Bn * Hn, 128, 0, stream>>>(QKV, Ob);
    // output projection
    cvt(sa_out_w + (size_t)i * Dn * Dn, Dn * Dn, Dn * Dn);
    k_gemm_bt<0><<<dim3(M / 128, Dn / 128), 256, 0, stream>>>(
        Ob, Wb, sa_out_b + i * Dn, Y, M, Dn, Dn, Dn);
    k_add_ln<0><<<M, 128, 0, stream>>>(X, Xb, Y, ln1_g + i * Dn, ln1_b + i * Dn);
    // cross-attention (precomputed broadcast) + LN2
    k_add_ln<1><<<M, 128, 0, stream>>>(X, Xb, ca_add + (size_t)i * Bn * Dn,
                                       ln2_g + i * Dn, ln2_b + i * Dn);
    // FFN
    cvt(ff1_w + (size_t)i * DFn * Dn, DFn * Dn, DFn * Dn);
    k_gemm_bt<1><<<dim3(M / 128, DFn / 128), 256, 0, stream>>>(
        Xb, Wb, ff1_b + i * DFn, H1b, M, DFn, Dn, DFn);
    cvt(ff2_w + (size_t)i * Dn * DFn, Dn * DFn, Dn * DFn);
    k_gemm_bt<0><<<dim3(M / 128, Dn / 128), 256, 0, stream>>>(
        H1b, Wb, ff2_b + i * Dn, Y, M, Dn, DFn, Dn);
    k_add_ln<0><<<M, 128, 0, stream>>>(X, Xb, Y, ln3_g + i * Dn, ln3_b + i * Dn);
  }

  // final vocab projection -> d_out (f32)
  cvt(op_w, Vn * Dn, VPAD * Dn);
  k_gemm_bt<0><<<dim3(M / 128, VPAD / 128), 256, 0, stream>>>(
      Xb, Wb, op_b, (float*)d_out, M, Vn, Dn, Vn);
}